// Round 1
// baseline (419.392 us; speedup 1.0000x reference)
//
#include <hip/hip_runtime.h>

#define B_TOT 8192
#define NPTS  128   // P
#define NF    4
#define NH    128
#define NC    32    // 2*LATENT
#define NPCS  20

typedef __attribute__((ext_vector_type(8))) short bf16x8;
typedef __attribute__((ext_vector_type(4))) float f32x4;

__device__ __forceinline__ short f2bf(float f) {
    union { float f; unsigned u; } v; v.f = f;
    unsigned r = v.u + 0x7FFFu + ((v.u >> 16) & 1u);  // RNE
    return (short)(r >> 16);
}

// LDS byte map (total 64128 < 65536):
// [0,      34816): sW2T short[128*136]      || union: sz float[32*129] (16512 B)
// [34816,  43520): sW3T short[32*136]
// [43520,  60928): sScr short[4][16*136]    || union: spw float[672] @43520, spool float[32] @46208
// [60928,  62976): sW1  float[512]
// [62976,  63488): sb1  float[128]
// [63488,  64000): sb2  float[128]
// [64000,  64128): sb3  float[32]

__global__ __launch_bounds__(256, 2) void enc_kernel(
    const float* __restrict__ x,  const float* __restrict__ W1, const float* __restrict__ b1,
    const float* __restrict__ W2, const float* __restrict__ b2, const float* __restrict__ W3,
    const float* __restrict__ b3, const float* __restrict__ pw, const float* __restrict__ eps,
    float* __restrict__ out)
{
    __shared__ __align__(16) char smem[64128];
    short* sW2T  = (short*)smem;                  // stride 136
    float* sz    = (float*)smem;                  // stride 129 (phase 2)
    short* sW3T  = (short*)(smem + 34816);        // stride 136
    short* sScr  = (short*)(smem + 43520);        // per-wave 16*136
    float* spw   = (float*)(smem + 43520);        // phase 2
    float* spool = (float*)(smem + 46208);        // phase 2
    float* sW1   = (float*)(smem + 60928);
    float* sb1   = (float*)(smem + 62976);
    float* sb2   = (float*)(smem + 63488);
    float* sb3   = (float*)(smem + 64000);

    const int tid  = threadIdx.x;
    const int b    = blockIdx.x;
    const int wv   = tid >> 6;
    const int lane = tid & 63;
    const int l16  = lane & 15;
    const int quad = lane >> 4;

    // ---------- Phase A: stage weights into LDS ----------
    for (int idx = tid; idx < NH * NH; idx += 256) {
        int k = idx >> 7, j = idx & 127;
        sW2T[j * 136 + k] = f2bf(W2[idx]);        // W2T[j][k] = W2[k][j]
    }
    for (int idx = tid; idx < NH * NC; idx += 256) {
        int k = idx >> 5, c = idx & 31;
        sW3T[c * 136 + k] = f2bf(W3[idx]);        // W3T[c][k] = W3[k][c]
    }
    for (int idx = tid; idx < NF * NH; idx += 256) sW1[idx] = W1[idx];
    if (tid < NH) { sb1[tid] = b1[tid]; sb2[tid] = b2[tid]; }
    if (tid < NC) sb3[tid] = b3[tid];
    __syncthreads();

    // ---------- GEMM1 (VALU, K=4): h1 A-frags in registers ----------
    // wave strip rows [wv*32, wv*32+32); m-tile mt row = wv*32 + mt*16 + l16
    const float4 xv0 = *(const float4*)(x + (size_t)b * 512 + (wv * 32 + l16) * 4);
    const float4 xv1 = *(const float4*)(x + (size_t)b * 512 + (wv * 32 + 16 + l16) * 4);

    bf16x8 a1[2][4];
#pragma unroll
    for (int kt = 0; kt < 4; ++kt) {
        const int k8 = kt * 32 + quad * 8;
#pragma unroll
        for (int j = 0; j < 8; ++j) {
            const float w0 = sW1[0 * 128 + k8 + j];
            const float w1v = sW1[1 * 128 + k8 + j];
            const float w2v = sW1[2 * 128 + k8 + j];
            const float w3v = sW1[3 * 128 + k8 + j];
            const float bv = sb1[k8 + j];
            float v0 = fmaf(xv0.x, w0, fmaf(xv0.y, w1v, fmaf(xv0.z, w2v, fmaf(xv0.w, w3v, bv))));
            float v1 = fmaf(xv1.x, w0, fmaf(xv1.y, w1v, fmaf(xv1.z, w2v, fmaf(xv1.w, w3v, bv))));
            a1[0][kt][j] = f2bf(fmaxf(v0, 0.0f));
            a1[1][kt][j] = f2bf(fmaxf(v1, 0.0f));
        }
    }

    // ---------- GEMM2 (MFMA bf16 16x16x32): h2 = relu(h1 @ W2 + b2) ----------
    f32x4 acc2[2][8];
#pragma unroll
    for (int mt = 0; mt < 2; ++mt)
#pragma unroll
        for (int nt = 0; nt < 8; ++nt) acc2[mt][nt] = (f32x4){0.f, 0.f, 0.f, 0.f};

#pragma unroll
    for (int kt = 0; kt < 4; ++kt) {
#pragma unroll
        for (int nt = 0; nt < 8; ++nt) {
            bf16x8 bf = *(const bf16x8*)&sW2T[(nt * 16 + l16) * 136 + kt * 32 + quad * 8];
            acc2[0][nt] = __builtin_amdgcn_mfma_f32_16x16x32_bf16(a1[0][kt], bf, acc2[0][nt], 0, 0, 0);
            acc2[1][nt] = __builtin_amdgcn_mfma_f32_16x16x32_bf16(a1[1][kt], bf, acc2[1][nt], 0, 0, 0);
        }
    }

    // ---------- GEMM3 (MFMA): h3 = h2 @ W3 + b3, via per-wave LDS scratch ----------
    f32x4 acc3[2][2];
    short* scr = sScr + wv * (16 * 136);
#pragma unroll
    for (int mt = 0; mt < 2; ++mt) {
        // epilogue h2 tile -> scratch (D layout: row=quad*4+r, col=nt*16+l16)
#pragma unroll
        for (int nt = 0; nt < 8; ++nt) {
            const int col = nt * 16 + l16;
            const float bb = sb2[col];
#pragma unroll
            for (int r = 0; r < 4; ++r) {
                float v = acc2[mt][nt][r] + bb;
                scr[(quad * 4 + r) * 136 + col] = f2bf(fmaxf(v, 0.0f));
            }
        }
        __syncthreads();  // cross-lane LDS dep (write->read within wave, be safe)

        bf16x8 a3[4];
#pragma unroll
        for (int kt = 0; kt < 4; ++kt)
            a3[kt] = *(const bf16x8*)&scr[l16 * 136 + kt * 32 + quad * 8];

#pragma unroll
        for (int nt = 0; nt < 2; ++nt) {
            f32x4 acc = (f32x4){0.f, 0.f, 0.f, 0.f};
#pragma unroll
            for (int kt = 0; kt < 4; ++kt) {
                bf16x8 bf = *(const bf16x8*)&sW3T[(nt * 16 + l16) * 136 + kt * 32 + quad * 8];
                acc = __builtin_amdgcn_mfma_f32_16x16x32_bf16(a3[kt], bf, acc, 0, 0, 0);
            }
            acc3[mt][nt] = acc;
        }
        __syncthreads();  // WAR: next mt rewrites scratch; also drains W2T reads before reuse
    }

    // ---------- write z = h3^T (+b3) into LDS (stride 129: conflict-free) ----------
#pragma unroll
    for (int mt = 0; mt < 2; ++mt)
#pragma unroll
        for (int nt = 0; nt < 2; ++nt) {
            const int c = nt * 16 + l16;
            const float bb = sb3[c];
#pragma unroll
            for (int r = 0; r < 4; ++r) {
                const int p = wv * 32 + mt * 16 + quad * 4 + r;
                sz[c * 129 + p] = acc3[mt][nt][r] + bb;
            }
        }
    // stage pool_weight into (now dead) scratch region
    for (int idx = tid; idx < NC * (NPCS + 1); idx += 256) spw[idx] = pw[idx];
    __syncthreads();

    // ---------- fspool positional weights (hoisted: depend only on lane) ----------
    const float pos0 = (float)lane / 127.0f * 20.0f;
    const float pos1 = (float)(lane + 64) / 127.0f * 20.0f;
    const int ip0 = min((int)pos0, NPCS), ip1 = min((int)pos1, NPCS);
    const float fr0 = pos0 - (float)ip0, fr1 = pos1 - (float)ip1;
    const int ip0b = min(ip0 + 1, NPCS), ip1b = min(ip1 + 1, NPCS);

    // ---------- per-row: in-register wave bitonic sort (descending) + weighted sum ----------
#pragma unroll
    for (int rr = 0; rr < 8; ++rr) {
        const int c = wv * 8 + rr;
        const float* zr = sz + c * 129;
        float v0 = zr[lane];        // element index i0 = lane
        float v1 = zr[lane + 64];   // element index i1 = lane + 64

#pragma unroll
        for (int k = 2; k <= 128; k <<= 1) {
#pragma unroll
            for (int j = 64; j > 0; j >>= 1) {
                if (j >= k) continue;
                if (j == 64) {  // only k==128: partners across slots, same lane, descending
                    float hi = fmaxf(v0, v1), lo = fminf(v0, v1);
                    v0 = hi; v1 = lo;
                } else {
                    const int i0 = lane, i1 = lane + 64;
                    float p0 = __shfl_xor(v0, j);
                    float p1 = __shfl_xor(v1, j);
                    const bool km0 = ((i0 & k) == 0) != ((i0 & j) != 0);
                    const bool km1 = ((i1 & k) == 0) != ((i1 & j) != 0);
                    v0 = km0 ? fmaxf(v0, p0) : fminf(v0, p0);
                    v1 = km1 ? fmaxf(v1, p1) : fminf(v1, p1);
                }
            }
        }

        // fspool weights for sorted positions lane, lane+64
        const float* pwr = spw + c * (NPCS + 1);
        const float w0 = (1.0f - fr0) * pwr[ip0] + fr0 * pwr[ip0b];
        const float w1 = (1.0f - fr1) * pwr[ip1] + fr1 * pwr[ip1b];
        float s = v0 * w0 + v1 * w1;
#pragma unroll
        for (int d = 32; d >= 1; d >>= 1) s += __shfl_xor(s, d);
        if (lane == 0) spool[c] = s;
    }
    __syncthreads();

    // ---------- outputs ----------
    if (tid < 16) {
        const float mu = spool[2 * tid];
        const float lv = spool[2 * tid + 1];
        const float e  = eps[(size_t)b * 16 + tid];
        const float smp = fmaf(e, expf(0.5f * lv), mu);
        out[(size_t)b * 16 + tid] = mu;
        out[(size_t)B_TOT * 16 + (size_t)b * 16 + tid] = lv;
        out[(size_t)2 * B_TOT * 16 + (size_t)b * 16 + tid] = smp;
    }
}

extern "C" void kernel_launch(void* const* d_in, const int* in_sizes, int n_in,
                              void* d_out, int out_size, void* d_ws, size_t ws_size,
                              hipStream_t stream) {
    const float* x   = (const float*)d_in[0];
    const float* W1  = (const float*)d_in[1];
    const float* b1  = (const float*)d_in[2];
    const float* W2  = (const float*)d_in[3];
    const float* b2  = (const float*)d_in[4];
    const float* W3  = (const float*)d_in[5];
    const float* b3  = (const float*)d_in[6];
    const float* pw  = (const float*)d_in[7];
    const float* eps = (const float*)d_in[8];
    float* out = (float*)d_out;

    enc_kernel<<<dim3(B_TOT), dim3(256), 0, stream>>>(x, W1, b1, W2, b2, W3, b3, pw, eps, out);
}

// Round 3
// 280.899 us; speedup vs baseline: 1.4930x; 1.4930x over previous
//
#include <hip/hip_runtime.h>

#define B_TOT 8192
#define NB    8          // batch elements per block
#define NPCS  20

typedef __attribute__((ext_vector_type(8))) short bf16x8;
typedef __attribute__((ext_vector_type(4))) float f32x4;
typedef __attribute__((ext_vector_type(2))) __fp16 fp16x2;

__device__ __forceinline__ short f2bf(float f) {
    union { float f; unsigned u; } v; v.f = f;
    unsigned r = v.u + 0x7FFFu + ((v.u >> 16) & 1u);  // RNE
    return (short)(r >> 16);
}
__device__ __forceinline__ unsigned pkmax(unsigned a, unsigned b) {
    unsigned d; asm("v_pk_max_f16 %0, %1, %2" : "=v"(d) : "v"(a), "v"(b)); return d;
}
__device__ __forceinline__ unsigned pkmin(unsigned a, unsigned b) {
    unsigned d; asm("v_pk_min_f16 %0, %1, %2" : "=v"(d) : "v"(a), "v"(b)); return d;
}
__device__ __forceinline__ float h2f(unsigned u) {   // converts low 16 bits
    float f; asm("v_cvt_f32_f16 %0, %1" : "=v"(f) : "v"(u)); return f;
}
__device__ __forceinline__ unsigned pkrtz(float a, float b) {
    fp16x2 h = __builtin_amdgcn_cvt_pkrtz(a, b);     // lo=a, hi=b
    return __builtin_bit_cast(unsigned, h);
}

// ---------------- d_ws layout (bytes) ----------------
// [0,     32768): W2T bf16 [128][128]   w2t[j*128+k] = bf16(W2[k][j])
// [32768, 40960): W3T bf16 [32][128]    w3t[c*128+k] = bf16(W3[k][c])
// [40960, 57344): wsp f32  [32][128]    precomputed fspool weights
// [57344, 59904): w1p float4[144]       padded idx h+(h>>3): {W1[0..3][h]}
#define WS_W3T 32768
#define WS_WSP 40960
#define WS_W1P 57344

__global__ void prep_kernel(const float* __restrict__ W1, const float* __restrict__ W2,
                            const float* __restrict__ W3, const float* __restrict__ pw,
                            void* __restrict__ ws)
{
    const int t = blockIdx.x * 256 + threadIdx.x;
    short* w2t = (short*)ws;
    short* w3t = (short*)((char*)ws + WS_W3T);
    float* wsp = (float*)((char*)ws + WS_WSP);
    float4* w1p = (float4*)((char*)ws + WS_W1P);
    if (t < 16384) {
        int j = t >> 7, k = t & 127;
        w2t[t] = f2bf(W2[k * 128 + j]);
    } else if (t < 20480) {
        int o = t - 16384, c = o >> 7, k = o & 127;
        w3t[o] = f2bf(W3[k * 32 + c]);
    } else if (t < 24576) {
        int o = t - 20480, c = o >> 7, p = o & 127;
        float pos = (float)p * (20.0f / 127.0f);
        int ip = min((int)pos, NPCS);
        float fr = pos - (float)ip;
        int ipb = min(ip + 1, NPCS);
        wsp[o] = (1.0f - fr) * pw[c * 21 + ip] + fr * pw[c * 21 + ipb];
    } else if (t < 24704) {
        int h = t - 24576;
        w1p[h + (h >> 3)] = make_float4(W1[h], W1[128 + h], W1[256 + h], W1[384 + h]);
    }
}

// ---------------- LDS layout (bytes, total 62464) ----------------
// [0,     32768): sW2T bf16, rows 256 B, chunk phys = ch ^ (row&15)  (xor swizzle)
// [32768, 50176): scr  bf16, per-wave 16 x 136 shorts (16B-aligned rows)
// [50176, 58624): szp  uint [16][132]  packed-f16 z pairs
// [58624, 60928): sw1  float4[144]
// [60928, 61440): sb1  f32[128]
// [61440, 62464): spool f32[NB*32]
#define L_SCR  32768
#define L_SZP  50176
#define L_W1P  58624
#define L_B1   60928
#define L_POOL 61440

__global__ __launch_bounds__(256, 2) void enc_kernel(
    const float* __restrict__ x,   const float* __restrict__ b1g,
    const float* __restrict__ b2g, const float* __restrict__ b3g,
    const float* __restrict__ eps, const void* __restrict__ ws,
    float* __restrict__ out)
{
    __shared__ __align__(16) char smem[62464];

    const int tid  = threadIdx.x;
    const int wv   = tid >> 6;
    const int lane = tid & 63;
    const int l16  = lane & 15;
    const int quad = lane >> 4;
    const int b0   = blockIdx.x * NB;

    // ---------- stage sW2T (xor-swizzled), w1 pack, b1 ----------
    {
        const uint4* src = (const uint4*)ws;     // 2048 16B chunks
#pragma unroll
        for (int it = 0; it < 8; ++it) {
            int idx = tid + it * 256;
            int j = idx >> 4, ch = idx & 15;
            int phys = ch ^ (j & 15);
            *(uint4*)(smem + j * 256 + phys * 16) = src[idx];
        }
    }
    if (tid < 144) ((float4*)(smem + L_W1P))[tid] = ((const float4*)((const char*)ws + WS_W1P))[tid];
    if (tid < 128) ((float*)(smem + L_B1))[tid] = b1g[tid];

    // ---------- hoisted register-resident data (persist across NB elements) ----------
    bf16x8 w3f[2][4];                                  // W3T A-frags
    {
        const short* w3t = (const short*)((const char*)ws + WS_W3T);
#pragma unroll
        for (int mt2 = 0; mt2 < 2; ++mt2)
#pragma unroll
            for (int kt = 0; kt < 4; ++kt)
                w3f[mt2][kt] = *(const bf16x8*)(w3t + (mt2 * 16 + l16) * 128 + kt * 32 + quad * 8);
    }
    float4 b3v[2];
    b3v[0] = *(const float4*)(b3g + quad * 4);
    b3v[1] = *(const float4*)(b3g + 16 + quad * 4);
    float b2r[8];
#pragma unroll
    for (int nt = 0; nt < 8; ++nt) b2r[nt] = b2g[nt * 16 + l16];

    __syncthreads();

    short*    scr   = (short*)(smem + L_SCR) + wv * (16 * 136);
    unsigned* szp   = (unsigned*)(smem + L_SZP);       // stride 132
    const float4* sw1 = (const float4*)(smem + L_W1P);
    const float*  sb1 = (const float*)(smem + L_B1);
    float*    spool = (float*)(smem + L_POOL);
    const float* wspg = (const float*)((const char*)ws + WS_WSP);

    for (int e = 0; e < NB; ++e) {
        const int b = b0 + e;

        // ---------- GEMM1 (VALU, K=4): h1 A-frags ----------
        const float4 xv0 = *(const float4*)(x + (size_t)b * 512 + (wv * 32 + l16) * 4);
        const float4 xv1 = *(const float4*)(x + (size_t)b * 512 + (wv * 32 + 16 + l16) * 4);
        bf16x8 a1[2][4];
#pragma unroll
        for (int kt = 0; kt < 4; ++kt) {
            const int k8 = kt * 32 + quad * 8;
#pragma unroll
            for (int j = 0; j < 8; ++j) {
                const int h = k8 + j;
                const float4 w = sw1[h + (h >> 3)];
                const float bb = sb1[h];
                float v0 = fmaf(xv0.x, w.x, fmaf(xv0.y, w.y, fmaf(xv0.z, w.z, fmaf(xv0.w, w.w, bb))));
                float v1 = fmaf(xv1.x, w.x, fmaf(xv1.y, w.y, fmaf(xv1.z, w.z, fmaf(xv1.w, w.w, bb))));
                a1[0][kt][j] = f2bf(fmaxf(v0, 0.0f));
                a1[1][kt][j] = f2bf(fmaxf(v1, 0.0f));
            }
        }

        // ---------- GEMM2 (MFMA): h2 = relu(h1 @ W2 + b2), bias pre-seeded ----------
        f32x4 acc2[2][8];
#pragma unroll
        for (int mt = 0; mt < 2; ++mt)
#pragma unroll
            for (int nt = 0; nt < 8; ++nt)
                acc2[mt][nt] = (f32x4){b2r[nt], b2r[nt], b2r[nt], b2r[nt]};
#pragma unroll
        for (int kt = 0; kt < 4; ++kt)
#pragma unroll
            for (int nt = 0; nt < 8; ++nt) {
                const int j = nt * 16 + l16;
                const int phys = (kt * 4 + quad) ^ l16;
                bf16x8 bf = *(const bf16x8*)(smem + j * 256 + phys * 16);
                acc2[0][nt] = __builtin_amdgcn_mfma_f32_16x16x32_bf16(a1[0][kt], bf, acc2[0][nt], 0, 0, 0);
                acc2[1][nt] = __builtin_amdgcn_mfma_f32_16x16x32_bf16(a1[1][kt], bf, acc2[1][nt], 0, 0, 0);
            }

        // ---------- GEMM3 transposed: z = W3T @ h2^T (+b3), via per-wave scr ----------
#pragma unroll
        for (int mt = 0; mt < 2; ++mt) {
            // h2 D-tile -> scr (bf16): row=p local (quad*4+r), col=k2
#pragma unroll
            for (int nt = 0; nt < 8; ++nt) {
                const int col = nt * 16 + l16;
#pragma unroll
                for (int r = 0; r < 4; ++r)
                    scr[(quad * 4 + r) * 136 + col] = f2bf(fmaxf(acc2[mt][nt][r], 0.0f));
            }
            asm volatile("s_waitcnt lgkmcnt(0)" ::: "memory");  // wave-local scr RAW

            bf16x8 a3[4];
#pragma unroll
            for (int kt = 0; kt < 4; ++kt)
                a3[kt] = *(const bf16x8*)(scr + l16 * 136 + kt * 32 + quad * 8);

            const int colbase = wv * 32 + mt * 16;
#pragma unroll
            for (int mt2 = 0; mt2 < 2; ++mt2) {
                f32x4 acc = (f32x4){b3v[mt2].x, b3v[mt2].y, b3v[mt2].z, b3v[mt2].w};
#pragma unroll
                for (int kt = 0; kt < 4; ++kt)
                    acc = __builtin_amdgcn_mfma_f32_16x16x32_bf16(w3f[mt2][kt], a3[kt], acc, 0, 0, 0);
                // lane holds z rows c = 16*mt2 + 4*quad + r, col p = colbase + l16
                const int pr = 8 * mt2 + 2 * quad;
                szp[pr * 132 + colbase + l16]       = pkrtz(acc[0], acc[1]);  // lo=even c (mu ch)
                szp[(pr + 1) * 132 + colbase + l16] = pkrtz(acc[2], acc[3]);
            }
            asm volatile("" ::: "memory");  // keep a3 reads ahead of next-mt scr writes
        }
        __syncthreads();  // all waves' z columns visible

        // ---------- packed-f16 bitonic sort (descending) + fspool ----------
        // wave owns pairs pr = wv*4 + q; elements i0=2*lane (v0), i1=2*lane+1 (v1)
        float2 wE[4], wO[4];
#pragma unroll
        for (int q = 0; q < 4; ++q) {
            const int pr = wv * 4 + q;
            wE[q] = *(const float2*)(wspg + (2 * pr) * 128 + 2 * lane);
            wO[q] = *(const float2*)(wspg + (2 * pr + 1) * 128 + 2 * lane);
        }
        unsigned v0[4], v1[4];
#pragma unroll
        for (int q = 0; q < 4; ++q) {
            const int pr = wv * 4 + q;
            uint2 z2 = *(const uint2*)(szp + pr * 132 + 2 * lane);
            v0[q] = z2.x; v1[q] = z2.y;
        }
        const int i0 = 2 * lane;
#pragma unroll
        for (int k = 2; k <= 128; k <<= 1) {
#pragma unroll
            for (int j = 64; j >= 1; j >>= 1) {
                if (j >= k) continue;
                if (j == 1) {
                    const bool km0 = ((i0 & k) == 0);
#pragma unroll
                    for (int q = 0; q < 4; ++q) {
                        unsigned mx = pkmax(v0[q], v1[q]);
                        unsigned mn = pkmin(v0[q], v1[q]);
                        v0[q] = km0 ? mx : mn;
                        v1[q] = km0 ? mn : mx;
                    }
                } else {
                    const int jm = j >> 1;
                    const bool km = ((i0 & k) == 0) != ((i0 & j) != 0);
#pragma unroll
                    for (int q = 0; q < 4; ++q) {
                        unsigned p0 = (unsigned)__shfl_xor((int)v0[q], jm);
                        unsigned p1 = (unsigned)__shfl_xor((int)v1[q], jm);
                        v0[q] = km ? pkmax(v0[q], p0) : pkmin(v0[q], p0);
                        v1[q] = km ? pkmax(v1[q], p1) : pkmin(v1[q], p1);
                    }
                }
            }
        }
        // weighted sums: low half = row 2pr (mu ch), high = row 2pr+1 (logvar ch)
        float sE[4], sO[4];
#pragma unroll
        for (int q = 0; q < 4; ++q) {
            float e0 = h2f(v0[q]), o0 = h2f(v0[q] >> 16);
            float e1 = h2f(v1[q]), o1 = h2f(v1[q] >> 16);
            sE[q] = wE[q].x * e0 + wE[q].y * e1;
            sO[q] = wO[q].x * o0 + wO[q].y * o1;
        }
#pragma unroll
        for (int d = 32; d >= 1; d >>= 1)
#pragma unroll
            for (int q = 0; q < 4; ++q) {
                sE[q] += __shfl_xor(sE[q], d);
                sO[q] += __shfl_xor(sO[q], d);
            }
        if (lane == 0) {
#pragma unroll
            for (int q = 0; q < 4; ++q) {
                const int pr = wv * 4 + q;
                spool[e * 32 + 2 * pr]     = sE[q];
                spool[e * 32 + 2 * pr + 1] = sO[q];
            }
        }
        __syncthreads();  // spool ready; also protects szp WAR for next element
    }

    // ---------- batched coalesced epilogue ----------
    if (tid < NB * 16) {
        const int e = tid >> 4, t = tid & 15;
        const float mu = spool[e * 32 + 2 * t];
        const float lv = spool[e * 32 + 2 * t + 1];
        const float ev = eps[(size_t)b0 * 16 + tid];
        const float smp = fmaf(ev, __expf(0.5f * lv), mu);
        out[(size_t)b0 * 16 + tid] = mu;
        out[(size_t)B_TOT * 16 + (size_t)b0 * 16 + tid] = lv;
        out[(size_t)2 * B_TOT * 16 + (size_t)b0 * 16 + tid] = smp;
    }
}

extern "C" void kernel_launch(void* const* d_in, const int* in_sizes, int n_in,
                              void* d_out, int out_size, void* d_ws, size_t ws_size,
                              hipStream_t stream) {
    const float* x   = (const float*)d_in[0];
    const float* W1  = (const float*)d_in[1];
    const float* b1  = (const float*)d_in[2];
    const float* W2  = (const float*)d_in[3];
    const float* b2  = (const float*)d_in[4];
    const float* W3  = (const float*)d_in[5];
    const float* b3  = (const float*)d_in[6];
    const float* pw  = (const float*)d_in[7];
    const float* eps = (const float*)d_in[8];
    float* out = (float*)d_out;

    prep_kernel<<<dim3(97), dim3(256), 0, stream>>>(W1, W2, W3, pw, d_ws);
    enc_kernel<<<dim3(B_TOT / NB), dim3(256), 0, stream>>>(x, b1, b2, b3, eps, d_ws, out);
}

// Round 4
// 193.477 us; speedup vs baseline: 2.1677x; 1.4518x over previous
//
#include <hip/hip_runtime.h>

#define B_TOT 8192
#define NB    16         // batch elements per block
#define NPCS  20

typedef __attribute__((ext_vector_type(8))) short bf16x8;
typedef __attribute__((ext_vector_type(4))) float f32x4;
typedef __attribute__((ext_vector_type(2))) __fp16 fp16x2;

__device__ __forceinline__ short f2bf(float f) {
    union { float f; unsigned u; } v; v.f = f;
    unsigned r = v.u + 0x7FFFu + ((v.u >> 16) & 1u);  // RNE
    return (short)(r >> 16);
}
__device__ __forceinline__ unsigned pkmax(unsigned a, unsigned b) {
    unsigned d; asm("v_pk_max_f16 %0, %1, %2" : "=v"(d) : "v"(a), "v"(b)); return d;
}
__device__ __forceinline__ unsigned pkmin(unsigned a, unsigned b) {
    unsigned d; asm("v_pk_min_f16 %0, %1, %2" : "=v"(d) : "v"(a), "v"(b)); return d;
}
__device__ __forceinline__ float h2f(unsigned u) {   // converts low 16 bits
    float f; asm("v_cvt_f32_f16 %0, %1" : "=v"(f) : "v"(u)); return f;
}
__device__ __forceinline__ unsigned pkrtz(float a, float b) {
    fp16x2 h = __builtin_amdgcn_cvt_pkrtz(a, b);     // lo=a, hi=b
    return __builtin_bit_cast(unsigned, h);
}
__device__ __forceinline__ float asf(unsigned u) { return __builtin_bit_cast(float, u); }
__device__ __forceinline__ unsigned asu(float f) { return __builtin_bit_cast(unsigned, f); }
// pack bf16-trunc(a) -> lo, bf16-trunc(b) -> hi  (2 VALU: lshr + and_or)
__device__ __forceinline__ unsigned packtr(float a, float b) {
    return (asu(a) >> 16) | (asu(b) & 0xffff0000u);
}

// ---------------- d_ws layout (bytes) ----------------
// [0,     32768): W2T bf16 [128][128]   w2t[j*128+k] = bf16(W2[k][j])
// [32768, 40960): W3T bf16 [32][128]    w3t[c*128+k] = bf16(W3[k][c])
// [40960, 57344): wsp f32  [32][128]    precomputed fspool weights
// [57344, 58368): w1b bf16x4 [128]      per h: {W1[0][h],W1[1][h],W1[2][h],W1[3][h]}
#define WS_W3T 32768
#define WS_WSP 40960
#define WS_W1B 57344

__global__ void prep_kernel(const float* __restrict__ W1, const float* __restrict__ W2,
                            const float* __restrict__ W3, const float* __restrict__ pw,
                            void* __restrict__ ws)
{
    const int t = blockIdx.x * 256 + threadIdx.x;
    short* w2t = (short*)ws;
    short* w3t = (short*)((char*)ws + WS_W3T);
    float* wsp = (float*)((char*)ws + WS_WSP);
    short* w1b = (short*)((char*)ws + WS_W1B);
    if (t < 16384) {
        int j = t >> 7, k = t & 127;
        w2t[t] = f2bf(W2[k * 128 + j]);
    } else if (t < 20480) {
        int o = t - 16384, c = o >> 7, k = o & 127;
        w3t[o] = f2bf(W3[k * 32 + c]);
    } else if (t < 24576) {
        int o = t - 20480, c = o >> 7, p = o & 127;
        float pos = (float)p * (20.0f / 127.0f);
        int ip = min((int)pos, NPCS);
        float fr = pos - (float)ip;
        int ipb = min(ip + 1, NPCS);
        wsp[o] = (1.0f - fr) * pw[c * 21 + ip] + fr * pw[c * 21 + ipb];
    } else if (t < 24704) {
        int h = t - 24576;
        w1b[h * 4 + 0] = f2bf(W1[h]);
        w1b[h * 4 + 1] = f2bf(W1[128 + h]);
        w1b[h * 4 + 2] = f2bf(W1[256 + h]);
        w1b[h * 4 + 3] = f2bf(W1[384 + h]);
    }
}

// ---------------- LDS layout (bytes, total 62208) ----------------
// [0,     32768): sW2T bf16, rows 256 B, chunk phys = ch ^ (row&15)  (xor swizzle)
// [32768, 50176): scr  bf16, per-wave 16 x 136 shorts
// [50176, 58624): szp  uint [16][132]  packed-f16 z pairs
// [58624, 59648): sw1b bf16x4 [128]
// [59648, 60160): sb1  f32[128]
// [60160, 62208): spool f32[NB*32]
#define L_SCR  32768
#define L_SZP  50176
#define L_W1B  58624
#define L_B1   59648
#define L_POOL 60160

__global__ __launch_bounds__(256, 2) void enc_kernel(
    const float* __restrict__ x,   const float* __restrict__ b1g,
    const float* __restrict__ b2g, const float* __restrict__ b3g,
    const float* __restrict__ eps, const void* __restrict__ ws,
    float* __restrict__ out)
{
    __shared__ __align__(16) char smem[62208];

    const int tid  = threadIdx.x;
    const int wv   = tid >> 6;
    const int lane = tid & 63;
    const int l16  = lane & 15;     // also lane-within-group for the sort
    const int quad = lane >> 4;
    const int b0   = blockIdx.x * NB;

    // ---------- stage sW2T (xor-swizzled), w1b, b1 ----------
    {
        const uint4* src = (const uint4*)ws;     // 2048 16B chunks
#pragma unroll
        for (int it = 0; it < 8; ++it) {
            int idx = tid + it * 256;
            int j = idx >> 4, ch = idx & 15;
            *(uint4*)(smem + j * 256 + ((ch ^ (j & 15)) * 16)) = src[idx];
        }
    }
    if (tid < 64)  ((uint4*)(smem + L_W1B))[tid] = ((const uint4*)((const char*)ws + WS_W1B))[tid];
    if (tid < 32)  ((float4*)(smem + L_B1))[tid] = ((const float4*)b1g)[tid];

    // ---------- hoisted register-resident data (persist across NB elements) ----------
    bf16x8 w3f[2][4];                                  // W3T A-frags
    {
        const short* w3t = (const short*)((const char*)ws + WS_W3T);
#pragma unroll
        for (int mt2 = 0; mt2 < 2; ++mt2)
#pragma unroll
            for (int kt = 0; kt < 4; ++kt)
                w3f[mt2][kt] = *(const bf16x8*)(w3t + (mt2 * 16 + l16) * 128 + kt * 32 + quad * 8);
    }
    float4 b3v[2];
    b3v[0] = *(const float4*)(b3g + quad * 4);
    b3v[1] = *(const float4*)(b3g + 16 + quad * 4);
    float b2r[8];
#pragma unroll
    for (int nt = 0; nt < 8; ++nt) b2r[nt] = b2g[nt * 16 + l16];

    // fspool weights for this lane's pair-row (element-invariant)
    const int pr = wv * 4 + quad;    // packed pair-row: channels 2pr (mu), 2pr+1 (logvar)
    float wE[8], wO[8];
    {
        const float* wsp = (const float*)((const char*)ws + WS_WSP);
        float4 e0 = *(const float4*)(wsp + (2 * pr) * 128 + l16 * 8);
        float4 e1 = *(const float4*)(wsp + (2 * pr) * 128 + l16 * 8 + 4);
        float4 o0 = *(const float4*)(wsp + (2 * pr + 1) * 128 + l16 * 8);
        float4 o1 = *(const float4*)(wsp + (2 * pr + 1) * 128 + l16 * 8 + 4);
        wE[0]=e0.x; wE[1]=e0.y; wE[2]=e0.z; wE[3]=e0.w; wE[4]=e1.x; wE[5]=e1.y; wE[6]=e1.z; wE[7]=e1.w;
        wO[0]=o0.x; wO[1]=o0.y; wO[2]=o0.z; wO[3]=o0.w; wO[4]=o1.x; wO[5]=o1.y; wO[6]=o1.z; wO[7]=o1.w;
    }
    __syncthreads();

    short*    scr   = (short*)(smem + L_SCR) + wv * (16 * 136);
    unsigned* szp   = (unsigned*)(smem + L_SZP);       // stride 132
    const float* sb1 = (const float*)(smem + L_B1);
    float*    spool = (float*)(smem + L_POOL);

    for (int e = 0; e < NB; ++e) {
        const int b = b0 + e;

        // ---------- GEMM1 (VALU, K=4): h1 A-frags, packed bf16 weights ----------
        const float4 xv0 = *(const float4*)(x + (size_t)b * 512 + (wv * 32 + l16) * 4);
        const float4 xv1 = *(const float4*)(x + (size_t)b * 512 + (wv * 32 + 16 + l16) * 4);
        union AF { unsigned u[4]; bf16x8 v; } a1[2][4];
#pragma unroll
        for (int kt = 0; kt < 4; ++kt) {
            const int k8 = kt * 32 + quad * 8;
            const float4 bb0 = *(const float4*)(sb1 + k8);
            const float4 bb1 = *(const float4*)(sb1 + k8 + 4);
            const float bias[8] = {bb0.x, bb0.y, bb0.z, bb0.w, bb1.x, bb1.y, bb1.z, bb1.w};
#pragma unroll
            for (int jp = 0; jp < 4; ++jp) {
                const uint4 wd = *(const uint4*)(smem + L_W1B + (k8 + 2 * jp) * 8);
                // h = k8+2jp: wd.x={w0,w1}, wd.y={w2,w3}; h+1: wd.z, wd.w
                const float wA0 = asf(wd.x << 16), wA1 = asf(wd.x & 0xffff0000u);
                const float wA2 = asf(wd.y << 16), wA3 = asf(wd.y & 0xffff0000u);
                const float wB0 = asf(wd.z << 16), wB1 = asf(wd.z & 0xffff0000u);
                const float wB2 = asf(wd.w << 16), wB3 = asf(wd.w & 0xffff0000u);
                float vA0 = fmaf(xv0.x, wA0, fmaf(xv0.y, wA1, fmaf(xv0.z, wA2, fmaf(xv0.w, wA3, bias[2*jp]))));
                float vA1 = fmaf(xv0.x, wB0, fmaf(xv0.y, wB1, fmaf(xv0.z, wB2, fmaf(xv0.w, wB3, bias[2*jp+1]))));
                float vB0 = fmaf(xv1.x, wA0, fmaf(xv1.y, wA1, fmaf(xv1.z, wA2, fmaf(xv1.w, wA3, bias[2*jp]))));
                float vB1 = fmaf(xv1.x, wB0, fmaf(xv1.y, wB1, fmaf(xv1.z, wB2, fmaf(xv1.w, wB3, bias[2*jp+1]))));
                a1[0][kt].u[jp] = packtr(fmaxf(vA0, 0.f), fmaxf(vA1, 0.f));
                a1[1][kt].u[jp] = packtr(fmaxf(vB0, 0.f), fmaxf(vB1, 0.f));
            }
        }

        // ---------- GEMM2 (MFMA): h2 = relu(h1 @ W2 + b2), bias pre-seeded ----------
        f32x4 acc2[2][8];
#pragma unroll
        for (int mt = 0; mt < 2; ++mt)
#pragma unroll
            for (int nt = 0; nt < 8; ++nt)
                acc2[mt][nt] = (f32x4){b2r[nt], b2r[nt], b2r[nt], b2r[nt]};
#pragma unroll
        for (int kt = 0; kt < 4; ++kt)
#pragma unroll
            for (int nt = 0; nt < 8; ++nt) {
                const int j = nt * 16 + l16;
                const int phys = (kt * 4 + quad) ^ l16;
                bf16x8 bf = *(const bf16x8*)(smem + j * 256 + phys * 16);
                acc2[0][nt] = __builtin_amdgcn_mfma_f32_16x16x32_bf16(a1[0][kt].v, bf, acc2[0][nt], 0, 0, 0);
                acc2[1][nt] = __builtin_amdgcn_mfma_f32_16x16x32_bf16(a1[1][kt].v, bf, acc2[1][nt], 0, 0, 0);
            }

        // ---------- GEMM3 transposed: z = W3T @ h2^T (+b3), via per-wave scr ----------
#pragma unroll
        for (int mt = 0; mt < 2; ++mt) {
#pragma unroll
            for (int nt = 0; nt < 8; ++nt) {
                const int col = nt * 16 + l16;
#pragma unroll
                for (int r = 0; r < 4; ++r)
                    scr[(quad * 4 + r) * 136 + col] = (short)(asu(fmaxf(acc2[mt][nt][r], 0.0f)) >> 16);
            }
            asm volatile("s_waitcnt lgkmcnt(0)" ::: "memory");  // wave-local scr RAW

            bf16x8 a3[4];
#pragma unroll
            for (int kt = 0; kt < 4; ++kt)
                a3[kt] = *(const bf16x8*)(scr + l16 * 136 + kt * 32 + quad * 8);

            const int colbase = wv * 32 + mt * 16;
#pragma unroll
            for (int mt2 = 0; mt2 < 2; ++mt2) {
                f32x4 acc = (f32x4){b3v[mt2].x, b3v[mt2].y, b3v[mt2].z, b3v[mt2].w};
#pragma unroll
                for (int kt = 0; kt < 4; ++kt)
                    acc = __builtin_amdgcn_mfma_f32_16x16x32_bf16(w3f[mt2][kt], a3[kt], acc, 0, 0, 0);
                // lane holds z rows c = 16*mt2 + 4*quad + r, col p = colbase + l16
                const int prw = 8 * mt2 + 2 * quad;
                szp[prw * 132 + colbase + l16]       = pkrtz(acc[0], acc[1]);  // lo=even c (mu ch)
                szp[(prw + 1) * 132 + colbase + l16] = pkrtz(acc[2], acc[3]);
            }
            asm volatile("" ::: "memory");  // keep a3 reads ahead of next-mt scr writes
        }
        __syncthreads();  // all waves' z columns visible

        // ---------- packed-f16 bitonic sort, 8 elems/lane over 16-lane groups ----------
        // group = quad; virtual element index i = l16*8 + r; full sort => input order free
        unsigned v[8];
        {
            const unsigned* zp = szp + pr * 132 + l16 * 8;
            uint4 za = *(const uint4*)zp;
            uint4 zb = *(const uint4*)(zp + 4);
            v[0]=za.x; v[1]=za.y; v[2]=za.z; v[3]=za.w;
            v[4]=zb.x; v[5]=zb.y; v[6]=zb.z; v[7]=zb.w;
        }
        const int ib = l16 * 8;
#pragma unroll
        for (int k = 2; k <= 128; k <<= 1) {
#pragma unroll
            for (int j = 64; j >= 1; j >>= 1) {
                if (j >= k) continue;
                if (j >= 8) {                       // cross-lane (within 16-lane group)
                    const bool km = ((ib & k) == 0) != ((ib & j) != 0);
                    const int lm = j >> 3;
#pragma unroll
                    for (int r = 0; r < 8; ++r) {
                        unsigned p = (unsigned)__shfl_xor((int)v[r], lm);
                        unsigned mx = pkmax(v[r], p), mn = pkmin(v[r], p);
                        v[r] = km ? mx : mn;
                    }
                } else if (k <= 4) {                // in-lane, static direction
#pragma unroll
                    for (int a = 0; a < 8; ++a) {
                        if (a & j) continue;
                        const int bx = a | j;
                        unsigned mx = pkmax(v[a], v[bx]), mn = pkmin(v[a], v[bx]);
                        if ((a & k) == 0) { v[a] = mx; v[bx] = mn; }
                        else              { v[a] = mn; v[bx] = mx; }
                    }
                } else {                            // in-lane, lane-dependent direction
                    const bool km = ((ib & k) == 0);
#pragma unroll
                    for (int a = 0; a < 8; ++a) {
                        if (a & j) continue;
                        const int bx = a | j;
                        unsigned mx = pkmax(v[a], v[bx]), mn = pkmin(v[a], v[bx]);
                        v[a] = km ? mx : mn;
                        v[bx] = km ? mn : mx;
                    }
                }
            }
        }

        // ---------- weighted sum + 16-lane group reduction ----------
        float sE = 0.f, sO = 0.f;
#pragma unroll
        for (int r = 0; r < 8; ++r) {
            sE = fmaf(wE[r], h2f(v[r]), sE);
            sO = fmaf(wO[r], h2f(v[r] >> 16), sO);
        }
#pragma unroll
        for (int d = 8; d >= 1; d >>= 1) {
            sE += __shfl_xor(sE, d);
            sO += __shfl_xor(sO, d);
        }
        if (l16 == 0) {
            spool[e * 32 + 2 * pr]     = sE;
            spool[e * 32 + 2 * pr + 1] = sO;
        }
        __syncthreads();  // spool ready; protects szp WAR for next element
    }

    // ---------- batched coalesced epilogue (NB*16 == 256) ----------
    {
        const int e = tid >> 4, t = tid & 15;
        const float mu = spool[e * 32 + 2 * t];
        const float lv = spool[e * 32 + 2 * t + 1];
        const float ev = eps[(size_t)b0 * 16 + tid];
        const float smp = fmaf(ev, __expf(0.5f * lv), mu);
        out[(size_t)b0 * 16 + tid] = mu;
        out[(size_t)B_TOT * 16 + (size_t)b0 * 16 + tid] = lv;
        out[(size_t)2 * B_TOT * 16 + (size_t)b0 * 16 + tid] = smp;
    }
}

extern "C" void kernel_launch(void* const* d_in, const int* in_sizes, int n_in,
                              void* d_out, int out_size, void* d_ws, size_t ws_size,
                              hipStream_t stream) {
    const float* x   = (const float*)d_in[0];
    const float* W1  = (const float*)d_in[1];
    const float* b1  = (const float*)d_in[2];
    const float* W2  = (const float*)d_in[3];
    const float* b2  = (const float*)d_in[4];
    const float* W3  = (const float*)d_in[5];
    const float* b3  = (const float*)d_in[6];
    const float* pw  = (const float*)d_in[7];
    const float* eps = (const float*)d_in[8];
    float* out = (float*)d_out;

    prep_kernel<<<dim3(97), dim3(256), 0, stream>>>(W1, W2, W3, pw, d_ws);
    enc_kernel<<<dim3(B_TOT / NB), dim3(256), 0, stream>>>(x, b1, b2, b3, eps, d_ws, out);
}